// Round 2
// baseline (2288.092 us; speedup 1.0000x reference)
//
#include <hip/hip_runtime.h>

#define BLOCK 256
#define ITEMS 8
#define CHUNK (BLOCK * ITEMS)
#define VMAX 2.2f

__device__ __forceinline__ float fast_tanh(float x) {
  // tanh(x) = 1 - 2/(exp(2x)+1); exact at +/-inf, ~1e-6 abs error.
  float e = __expf(2.0f * x);
  return 1.0f - 2.0f / (e + 1.0f);
}

__device__ __forceinline__ void atom_store_d(double* p, double v) {
  atomicExch((unsigned long long*)p, (unsigned long long)__double_as_longlong(v));
}
__device__ __forceinline__ double atom_load_d(double* p) {
  unsigned long long u = atomicAdd((unsigned long long*)p, 0ULL);
  return __longlong_as_double((long long)u);
}

// Single-pass decoupled-lookback scan + fused elementwise emit.
// vals[tile*4 + {0,1}] = aggregate (x,y); vals[tile*4 + {2,3}] = inclusive (x,y)
// flags: 0 = invalid, 1 = aggregate ready, 2 = inclusive ready.
__global__ __launch_bounds__(BLOCK) void wi_scan_single(
    const float* __restrict__ U, const float* __restrict__ x0,
    const float* __restrict__ dtp,
    int* __restrict__ counter, int* __restrict__ flags,
    double* __restrict__ vals, float* __restrict__ out,
    int N, int ntiles)
{
  __shared__ int s_tile;
  __shared__ double lsx[BLOCK], lsy[BLOCK];
  __shared__ double s_ex, s_ey;

  const int t = threadIdx.x;
  if (t == 0) s_tile = atomicAdd(counter, 1);  // ticket: tiles assigned in start order
  __syncthreads();
  const int tile = s_tile;
  const long base = (long)tile * CHUNK + (long)t * ITEMS;
  const float dt = *dtp;

  float vx[ITEMS], vy[ITEMS];
  const bool full = (base + ITEMS <= (long)N);
  if (full) {
    const float4* p = (const float4*)(U + 2 * base);  // lane reads exactly one 64B line
    #pragma unroll
    for (int i = 0; i < ITEMS / 2; ++i) {
      float4 a = p[i];
      vx[2*i]   = fast_tanh(a.x) * VMAX; vy[2*i]   = fast_tanh(a.y) * VMAX;
      vx[2*i+1] = fast_tanh(a.z) * VMAX; vy[2*i+1] = fast_tanh(a.w) * VMAX;
    }
  } else {
    for (int i = 0; i < ITEMS; ++i) {
      long idx = base + i;
      if (idx < N) { vx[i] = fast_tanh(U[2*idx]) * VMAX; vy[i] = fast_tanh(U[2*idx+1]) * VMAX; }
      else { vx[i] = 0.f; vy[i] = 0.f; }
    }
  }

  // thread-local inclusive prefix (fp32, small magnitude)
  float px[ITEMS], py[ITEMS];
  float sx = 0.f, sy = 0.f;
  #pragma unroll
  for (int i = 0; i < ITEMS; ++i) { sx += vx[i]*dt; px[i] = sx; sy += vy[i]*dt; py[i] = sy; }

  // block-wide inclusive Hillis-Steele scan of thread totals (fp64)
  lsx[t] = (double)sx; lsy[t] = (double)sy;
  __syncthreads();
  #pragma unroll
  for (int off = 1; off < BLOCK; off <<= 1) {
    double ax = lsx[t], ay = lsy[t];
    double bx = (t >= off) ? lsx[t-off] : 0.0;
    double by = (t >= off) ? lsy[t-off] : 0.0;
    __syncthreads();
    lsx[t] = ax + bx; lsy[t] = ay + by;
    __syncthreads();
  }
  const float exb = (t > 0) ? (float)lsx[t-1] : 0.f;  // exclusive within tile
  const float eyb = (t > 0) ? (float)lsy[t-1] : 0.f;

  // wave 0: publish aggregate, decoupled lookback, publish inclusive
  if (t < 64) {
    const double aggx = lsx[BLOCK-1], aggy = lsy[BLOCK-1];
    double* vt = vals + (size_t)tile * 4;
    if (t == 0) {
      if (tile == 0) {
        atom_store_d(vt+2, aggx); atom_store_d(vt+3, aggy);
        __threadfence();
        atomicExch(flags + tile, 2);
      } else {
        atom_store_d(vt+0, aggx); atom_store_d(vt+1, aggy);
        __threadfence();
        atomicExch(flags + tile, 1);
      }
    }
    double accx = 0.0, accy = 0.0;
    if (tile > 0) {
      int look = tile - 1;
      while (true) {
        const int idx = look - t;
        const bool valid = (idx >= 0);
        int f;
        do { f = valid ? atomicAdd(flags + idx, 0) : 2; }
        while (__ballot(f == 0));
        __threadfence();
        const unsigned long long m2 = __ballot(valid && (f == 2));
        double* v = vals + (size_t)idx * 4;
        if (m2) {
          const int L = __ffsll(m2) - 1;  // closest predecessor with inclusive
          if (t < L)       { accx += atom_load_d(v+0); accy += atom_load_d(v+1); }
          else if (t == L) { accx += atom_load_d(v+2); accy += atom_load_d(v+3); }
          break;
        } else {
          if (valid) { accx += atom_load_d(v+0); accy += atom_load_d(v+1); }
          look -= 64;
        }
      }
      #pragma unroll
      for (int o = 1; o < 64; o <<= 1) {
        accx += __shfl_xor(accx, o);
        accy += __shfl_xor(accy, o);
      }
      if (t == 0) {
        atom_store_d(vt+2, accx + aggx); atom_store_d(vt+3, accy + aggy);
        __threadfence();
        atomicExch(flags + tile, 2);
      }
    }
    if (t == 0) { s_ex = accx; s_ey = accy; }
  }
  __syncthreads();

  const double ox = s_ex + (double)x0[0];
  const double oy = s_ey + (double)x0[1];
  float4* o4 = (float4*)out;
  if (full) {
    #pragma unroll
    for (int i = 0; i < ITEMS; ++i) {
      float posx = (float)(ox + (double)(exb + px[i]));
      float posy = (float)(oy + (double)(eyb + py[i]));
      float th = atan2f(vy[i], vx[i] + 1e-9f);
      float vv = fminf(sqrtf(vx[i]*vx[i] + vy[i]*vy[i] + 1e-12f), VMAX);
      o4[1 + base + i] = make_float4(posx, posy, th, vv);
    }
  } else {
    for (int i = 0; i < ITEMS; ++i) {
      long idx = base + i;
      if (idx < N) {
        float posx = (float)(ox + (double)(exb + px[i]));
        float posy = (float)(oy + (double)(eyb + py[i]));
        float th = atan2f(vy[i], vx[i] + 1e-9f);
        float vv = fminf(sqrtf(vx[i]*vx[i] + vy[i]*vy[i] + 1e-12f), VMAX);
        o4[1 + idx] = make_float4(posx, posy, th, vv);
      }
    }
  }
  if (tile == 0 && t == 0) {
    o4[0] = make_float4(x0[0], x0[1], x0[2], x0[3]);
  }
}

extern "C" void kernel_launch(void* const* d_in, const int* in_sizes, int n_in,
                              void* d_out, int out_size, void* d_ws, size_t ws_size,
                              hipStream_t stream) {
  const float* x0 = (const float*)d_in[0];
  const float* U  = (const float*)d_in[1];
  const float* dt = (const float*)d_in[2];
  float* out = (float*)d_out;
  const int N = in_sizes[1] / 2;
  const int ntiles = (N + CHUNK - 1) / CHUNK;  // 8192 for H=16.7M

  char* ws = (char*)d_ws;
  int* counter = (int*)ws;                                    // 1 int
  int* flags = (int*)(ws + 64);                               // ntiles ints
  size_t vals_off = (64 + (size_t)ntiles * 4 + 15) & ~(size_t)15;
  double* vals = (double*)(ws + vals_off);                    // ntiles * 4 doubles

  // reset ticket counter + flags each call (deterministic, graph-capture safe)
  hipMemsetAsync(d_ws, 0, vals_off, stream);
  wi_scan_single<<<ntiles, BLOCK, 0, stream>>>(U, x0, dt, counter, flags, vals, out, N, ntiles);
}

// Round 4
// 753.766 us; speedup vs baseline: 3.0355x; 3.0355x over previous
//
#include <hip/hip_runtime.h>

#define B1 256
#define IT1 8                 // pairs per thread, kernel 1 (64B/lane)
#define CH1 (B1 * IT1)
#define B3 256
#define IT3 8                 // pairs per thread, kernel 3
#define CH3 (B3 * IT3)
#define B2 1024
#define VMAX 2.2f

typedef float f32x4 __attribute__((ext_vector_type(4)));

struct DSum { double x, y; };

__device__ __forceinline__ float fast_tanh(float x) {
  // tanh(x) = 1 - 2/(exp(2x)+1); exact at +/-inf, ~1e-6 abs error.
  float e = __expf(2.0f * x);
  return 1.0f - 2.0f / (e + 1.0f);
}

// Kernel 1: per-block partial sums of tanh(U)*vmax*dt (fp32 in-block, fp64 out).
__global__ __launch_bounds__(B1) void wi_partial(
    const float* __restrict__ U, const float* __restrict__ dtp,
    DSum* __restrict__ bsum, int N)
{
  const int t = threadIdx.x;
  const int lane = t & 63, wid = t >> 6;
  const long base = (long)blockIdx.x * CH1 + (long)t * IT1;
  float sx = 0.f, sy = 0.f;
  if (base + IT1 <= (long)N) {
    const f32x4* p = (const f32x4*)(U + 2 * base);
    #pragma unroll
    for (int i = 0; i < IT1 / 2; ++i) {
      f32x4 a = p[i];
      sx += fast_tanh(a.x) + fast_tanh(a.z);
      sy += fast_tanh(a.y) + fast_tanh(a.w);
    }
  } else {
    for (int i = 0; i < IT1; ++i) {
      long idx = base + i;
      if (idx < N) { sx += fast_tanh(U[2*idx]); sy += fast_tanh(U[2*idx+1]); }
    }
  }
  // wave butterfly reduce (fp32)
  #pragma unroll
  for (int o = 1; o < 64; o <<= 1) { sx += __shfl_xor(sx, o); sy += __shfl_xor(sy, o); }
  __shared__ double wsx[B1/64], wsy[B1/64];
  if (lane == 0) { wsx[wid] = (double)sx; wsy[wid] = (double)sy; }
  __syncthreads();
  if (t == 0) {
    const float sc = VMAX * (*dtp);
    double ax = 0.0, ay = 0.0;
    #pragma unroll
    for (int w = 0; w < B1/64; ++w) { ax += wsx[w]; ay += wsy[w]; }
    bsum[blockIdx.x].x = ax * (double)sc;
    bsum[blockIdx.x].y = ay * (double)sc;
  }
}

// Kernel 2: single-block fp64 exclusive scan of block sums (in place).
__global__ __launch_bounds__(B2) void wi_scan_blocks(DSum* bsum, int nblocks)
{
  const int t = threadIdx.x;
  const int per = (nblocks + B2 - 1) / B2;
  const int s = t * per;
  const int e = min(s + per, nblocks);
  double tx = 0.0, ty = 0.0;
  for (int i = s; i < e; ++i) { tx += bsum[i].x; ty += bsum[i].y; }
  __shared__ double lx[B2], ly[B2];
  lx[t] = tx; ly[t] = ty;
  __syncthreads();
  for (int off = 1; off < B2; off <<= 1) {
    double ax = lx[t], ay = ly[t];
    double bx = (t >= off) ? lx[t - off] : 0.0;
    double by = (t >= off) ? ly[t - off] : 0.0;
    __syncthreads();
    lx[t] = ax + bx; ly[t] = ay + by;
    __syncthreads();
  }
  double rx = (t > 0) ? lx[t - 1] : 0.0;
  double ry = (t > 0) ? ly[t - 1] : 0.0;
  for (int i = s; i < e; ++i) {
    double vx = bsum[i].x, vy = bsum[i].y;
    bsum[i].x = rx; bsum[i].y = ry;
    rx += vx; ry += vy;
  }
}

// Kernel 3: recompute uv, wave-shuffle scan, emit [pos, theta, v].
__global__ __launch_bounds__(B3) void wi_emit(
    const float* __restrict__ U, const float* __restrict__ x0,
    const float* __restrict__ dtp, const DSum* __restrict__ boff,
    float* __restrict__ out, int N)
{
  const int t = threadIdx.x;
  const int lane = t & 63, wid = t >> 6;
  const long base = (long)blockIdx.x * CH3 + (long)t * IT3;
  const float dt = *dtp;

  float vx[IT3], vy[IT3];
  const bool full = (base + IT3 <= (long)N);
  if (full) {
    const f32x4* p = (const f32x4*)(U + 2 * base);
    #pragma unroll
    for (int i = 0; i < IT3 / 2; ++i) {
      f32x4 a = p[i];
      vx[2*i]   = fast_tanh(a.x) * VMAX; vy[2*i]   = fast_tanh(a.y) * VMAX;
      vx[2*i+1] = fast_tanh(a.z) * VMAX; vy[2*i+1] = fast_tanh(a.w) * VMAX;
    }
  } else {
    for (int i = 0; i < IT3; ++i) {
      long idx = base + i;
      if (idx < N) { vx[i] = fast_tanh(U[2*idx]) * VMAX; vy[i] = fast_tanh(U[2*idx+1]) * VMAX; }
      else { vx[i] = 0.f; vy[i] = 0.f; }
    }
  }

  // thread-local inclusive prefix of uv*dt (fp32)
  float px[IT3], py[IT3];
  float sx = 0.f, sy = 0.f;
  #pragma unroll
  for (int i = 0; i < IT3; ++i) { sx += vx[i]*dt; px[i] = sx; sy += vy[i]*dt; py[i] = sy; }
  const float totx = sx, toty = sy;

  // wave-level inclusive scan of thread totals (fp32; tile sums ~<=225, fine)
  #pragma unroll
  for (int o = 1; o < 64; o <<= 1) {
    float ux = __shfl_up(sx, o);
    float uy = __shfl_up(sy, o);
    if (lane >= o) { sx += ux; sy += uy; }
  }
  __shared__ float wsum_x[B3/64], wsum_y[B3/64];
  if (lane == 63) { wsum_x[wid] = sx; wsum_y[wid] = sy; }
  __syncthreads();
  float wbx = 0.f, wby = 0.f;
  #pragma unroll
  for (int w = 0; w < B3/64; ++w) {
    if (w < wid) { wbx += wsum_x[w]; wby += wsum_y[w]; }
  }
  const float exb = wbx + sx - totx;   // exclusive prefix within tile
  const float eyb = wby + sy - toty;

  const double ox = boff[blockIdx.x].x + (double)x0[0];
  const double oy = boff[blockIdx.x].y + (double)x0[1];
  f32x4* o4 = (f32x4*)out;
  #pragma unroll
  for (int i = 0; i < IT3; ++i) {
    long idx = base + i;
    if (full || idx < N) {
      float posx = (float)(ox + (double)(exb + px[i]));
      float posy = (float)(oy + (double)(eyb + py[i]));
      float th = atan2f(vy[i], vx[i] + 1e-9f);
      float vv = fminf(sqrtf(vx[i]*vx[i] + vy[i]*vy[i] + 1e-12f), VMAX);
      f32x4 r; r.x = posx; r.y = posy; r.z = th; r.w = vv;
      __builtin_nontemporal_store(r, o4 + 1 + idx);
    }
  }
  if (blockIdx.x == 0 && t == 0) {
    f32x4 r; r.x = x0[0]; r.y = x0[1]; r.z = x0[2]; r.w = x0[3];
    o4[0] = r;
  }
}

extern "C" void kernel_launch(void* const* d_in, const int* in_sizes, int n_in,
                              void* d_out, int out_size, void* d_ws, size_t ws_size,
                              hipStream_t stream) {
  const float* x0 = (const float*)d_in[0];
  const float* U  = (const float*)d_in[1];
  const float* dt = (const float*)d_in[2];
  float* out = (float*)d_out;
  const int N = in_sizes[1] / 2;
  const int nb1 = (N + CH1 - 1) / CH1;   // 8192
  const int nb3 = (N + CH3 - 1) / CH3;   // 8192 (CH1 == CH3)
  DSum* bsum = (DSum*)d_ws;              // nb1 * 16 B = 128 KiB

  wi_partial<<<nb1, B1, 0, stream>>>(U, dt, bsum, N);
  wi_scan_blocks<<<1, B2, 0, stream>>>(bsum, nb1);
  wi_emit<<<nb3, B3, 0, stream>>>(U, x0, dt, bsum, out, N);
}

// Round 5
// 112.167 us; speedup vs baseline: 20.3990x; 6.7201x over previous
//
#include <hip/hip_runtime.h>

#define B1 256
#define IT1 8                 // pairs per thread, kernel 1 (64B/lane)
#define CH1 (B1 * IT1)
#define B3 256
#define IT3 8                 // pairs per thread, kernel 3
#define CH3 (B3 * IT3)
#define B2 1024
#define VMAX 2.2f

typedef float f32x4 __attribute__((ext_vector_type(4)));

struct DSum { double x, y; };

__device__ __forceinline__ float fast_tanh(float x) {
  // tanh(x) = 1 - 2/(exp(2x)+1); exact at +/-inf, ~1e-6 abs error.
  float e = __expf(2.0f * x);
  return 1.0f - 2.0f / (e + 1.0f);
}

// Kernel 1: per-block partial sums of tanh(U)*vmax*dt (fp32 in-block, fp64 out).
__global__ __launch_bounds__(B1) void wi_partial(
    const float* __restrict__ U, const float* __restrict__ dtp,
    DSum* __restrict__ bsum, int N)
{
  const int t = threadIdx.x;
  const int lane = t & 63, wid = t >> 6;
  const long base = (long)blockIdx.x * CH1 + (long)t * IT1;
  float sx = 0.f, sy = 0.f;
  if (base + IT1 <= (long)N) {
    const f32x4* p = (const f32x4*)(U + 2 * base);
    #pragma unroll
    for (int i = 0; i < IT1 / 2; ++i) {
      f32x4 a = p[i];
      sx += fast_tanh(a.x) + fast_tanh(a.z);
      sy += fast_tanh(a.y) + fast_tanh(a.w);
    }
  } else {
    for (int i = 0; i < IT1; ++i) {
      long idx = base + i;
      if (idx < N) { sx += fast_tanh(U[2*idx]); sy += fast_tanh(U[2*idx+1]); }
    }
  }
  // wave butterfly reduce (fp32)
  #pragma unroll
  for (int o = 1; o < 64; o <<= 1) { sx += __shfl_xor(sx, o); sy += __shfl_xor(sy, o); }
  __shared__ double wsx[B1/64], wsy[B1/64];
  if (lane == 0) { wsx[wid] = (double)sx; wsy[wid] = (double)sy; }
  __syncthreads();
  if (t == 0) {
    const float sc = VMAX * (*dtp);
    double ax = 0.0, ay = 0.0;
    #pragma unroll
    for (int w = 0; w < B1/64; ++w) { ax += wsx[w]; ay += wsy[w]; }
    bsum[blockIdx.x].x = ax * (double)sc;
    bsum[blockIdx.x].y = ay * (double)sc;
  }
}

// Kernel 2: single-block fp64 exclusive scan of block sums (in place).
__global__ __launch_bounds__(B2) void wi_scan_blocks(DSum* bsum, int nblocks)
{
  const int t = threadIdx.x;
  const int per = (nblocks + B2 - 1) / B2;
  const int s = t * per;
  const int e = min(s + per, nblocks);
  double tx = 0.0, ty = 0.0;
  for (int i = s; i < e; ++i) { tx += bsum[i].x; ty += bsum[i].y; }
  __shared__ double lx[B2], ly[B2];
  lx[t] = tx; ly[t] = ty;
  __syncthreads();
  for (int off = 1; off < B2; off <<= 1) {
    double ax = lx[t], ay = ly[t];
    double bx = (t >= off) ? lx[t - off] : 0.0;
    double by = (t >= off) ? ly[t - off] : 0.0;
    __syncthreads();
    lx[t] = ax + bx; ly[t] = ay + by;
    __syncthreads();
  }
  double rx = (t > 0) ? lx[t - 1] : 0.0;
  double ry = (t > 0) ? ly[t - 1] : 0.0;
  for (int i = s; i < e; ++i) {
    double vx = bsum[i].x, vy = bsum[i].y;
    bsum[i].x = rx; bsum[i].y = ry;
    rx += vx; ry += vy;
  }
}

// Kernel 3: recompute uv, wave-shuffle scan, stage rows in LDS, emit with
// wave-contiguous cached stores (each store instr = 1024 contiguous B/wave).
__global__ __launch_bounds__(B3) void wi_emit(
    const float* __restrict__ U, const float* __restrict__ x0,
    const float* __restrict__ dtp, const DSum* __restrict__ boff,
    float* __restrict__ out, int N)
{
  __shared__ f32x4 stage[CH3];        // 2048 * 16 B = 32 KiB
  __shared__ float wsum_x[B3/64], wsum_y[B3/64];

  const int t = threadIdx.x;
  const int lane = t & 63, wid = t >> 6;
  const long base = (long)blockIdx.x * CH3 + (long)t * IT3;
  const float dt = *dtp;

  float vx[IT3], vy[IT3];
  const bool full = (base + IT3 <= (long)N);
  if (full) {
    const f32x4* p = (const f32x4*)(U + 2 * base);
    #pragma unroll
    for (int i = 0; i < IT3 / 2; ++i) {
      f32x4 a = p[i];
      vx[2*i]   = fast_tanh(a.x) * VMAX; vy[2*i]   = fast_tanh(a.y) * VMAX;
      vx[2*i+1] = fast_tanh(a.z) * VMAX; vy[2*i+1] = fast_tanh(a.w) * VMAX;
    }
  } else {
    for (int i = 0; i < IT3; ++i) {
      long idx = base + i;
      if (idx < N) { vx[i] = fast_tanh(U[2*idx]) * VMAX; vy[i] = fast_tanh(U[2*idx+1]) * VMAX; }
      else { vx[i] = 0.f; vy[i] = 0.f; }
    }
  }

  // thread-local inclusive prefix of uv*dt (fp32)
  float px[IT3], py[IT3];
  float sx = 0.f, sy = 0.f;
  #pragma unroll
  for (int i = 0; i < IT3; ++i) { sx += vx[i]*dt; px[i] = sx; sy += vy[i]*dt; py[i] = sy; }
  const float totx = sx, toty = sy;

  // wave-level inclusive scan of thread totals (fp32; tile sums small)
  #pragma unroll
  for (int o = 1; o < 64; o <<= 1) {
    float ux = __shfl_up(sx, o);
    float uy = __shfl_up(sy, o);
    if (lane >= o) { sx += ux; sy += uy; }
  }
  if (lane == 63) { wsum_x[wid] = sx; wsum_y[wid] = sy; }
  __syncthreads();
  float wbx = 0.f, wby = 0.f;
  #pragma unroll
  for (int w = 0; w < B3/64; ++w) {
    if (w < wid) { wbx += wsum_x[w]; wby += wsum_y[w]; }
  }
  const float exb = wbx + sx - totx;   // exclusive prefix within tile
  const float eyb = wby + sy - toty;

  const double ox = boff[blockIdx.x].x + (double)x0[0];
  const double oy = boff[blockIdx.x].y + (double)x0[1];

  // compute rows into LDS (XOR-swizzled so blocked writes + contiguous reads
  // both spread across bank groups)
  #pragma unroll
  for (int i = 0; i < IT3; ++i) {
    float posx = (float)(ox + (double)(exb + px[i]));
    float posy = (float)(oy + (double)(eyb + py[i]));
    float th = atan2f(vy[i], vx[i] + 1e-9f);
    float vv = fminf(sqrtf(vx[i]*vx[i] + vy[i]*vy[i] + 1e-12f), VMAX);
    f32x4 r; r.x = posx; r.y = posy; r.z = th; r.w = vv;
    const int k = t * IT3 + i;
    stage[k ^ ((k >> 3) & 7)] = r;
  }
  __syncthreads();

  // cooperative wave-contiguous stores
  const long tile0 = (long)blockIdx.x * CH3;
  f32x4* o4 = (f32x4*)out;
  #pragma unroll
  for (int i = 0; i < IT3; ++i) {
    const int k = i * B3 + t;
    const long g = tile0 + k;
    if (g < (long)N) o4[1 + g] = stage[k ^ ((k >> 3) & 7)];
  }
  if (blockIdx.x == 0 && t == 0) {
    f32x4 r; r.x = x0[0]; r.y = x0[1]; r.z = x0[2]; r.w = x0[3];
    o4[0] = r;
  }
}

extern "C" void kernel_launch(void* const* d_in, const int* in_sizes, int n_in,
                              void* d_out, int out_size, void* d_ws, size_t ws_size,
                              hipStream_t stream) {
  const float* x0 = (const float*)d_in[0];
  const float* U  = (const float*)d_in[1];
  const float* dt = (const float*)d_in[2];
  float* out = (float*)d_out;
  const int N = in_sizes[1] / 2;
  const int nb1 = (N + CH1 - 1) / CH1;   // 8192
  const int nb3 = (N + CH3 - 1) / CH3;   // 8192 (CH1 == CH3)
  DSum* bsum = (DSum*)d_ws;              // nb1 * 16 B = 128 KiB

  wi_partial<<<nb1, B1, 0, stream>>>(U, dt, bsum, N);
  wi_scan_blocks<<<1, B2, 0, stream>>>(bsum, nb1);
  wi_emit<<<nb3, B3, 0, stream>>>(U, x0, dt, bsum, out, N);
}

// Round 6
// 109.360 us; speedup vs baseline: 20.9225x; 1.0257x over previous
//
#include <hip/hip_runtime.h>

#define B1 256
#define IT1 8                 // pairs per thread, kernel 1 (64B/lane)
#define CH1 (B1 * IT1)
#define B3 256
#define IT3 8                 // pairs per thread, kernel 3
#define CH3 (B3 * IT3)
#define B2 1024
#define VMAX 2.2f

typedef float f32x4 __attribute__((ext_vector_type(4)));

struct DSum { double x, y; };

__device__ __forceinline__ float fast_tanh(float x) {
  // tanh(x) = 1 - 2/(exp(2x)+1); exact at +/-inf, ~1e-6 abs error.
  float e = __expf(2.0f * x);
  return 1.0f - 2.0f / (e + 1.0f);
}

// Kernel 1: per-block partial sums of tanh(U)*vmax*dt (fp32 in-block, fp64 out).
__global__ __launch_bounds__(B1) void wi_partial(
    const float* __restrict__ U, const float* __restrict__ dtp,
    DSum* __restrict__ bsum, int N)
{
  const int t = threadIdx.x;
  const int lane = t & 63, wid = t >> 6;
  const long base = (long)blockIdx.x * CH1 + (long)t * IT1;
  float sx = 0.f, sy = 0.f;
  if (base + IT1 <= (long)N) {
    const f32x4* p = (const f32x4*)(U + 2 * base);
    #pragma unroll
    for (int i = 0; i < IT1 / 2; ++i) {
      f32x4 a = p[i];
      sx += fast_tanh(a.x) + fast_tanh(a.z);
      sy += fast_tanh(a.y) + fast_tanh(a.w);
    }
  } else {
    for (int i = 0; i < IT1; ++i) {
      long idx = base + i;
      if (idx < N) { sx += fast_tanh(U[2*idx]); sy += fast_tanh(U[2*idx+1]); }
    }
  }
  // wave butterfly reduce (fp32)
  #pragma unroll
  for (int o = 1; o < 64; o <<= 1) { sx += __shfl_xor(sx, o); sy += __shfl_xor(sy, o); }
  __shared__ double wsx[B1/64], wsy[B1/64];
  if (lane == 0) { wsx[wid] = (double)sx; wsy[wid] = (double)sy; }
  __syncthreads();
  if (t == 0) {
    const float sc = VMAX * (*dtp);
    double ax = 0.0, ay = 0.0;
    #pragma unroll
    for (int w = 0; w < B1/64; ++w) { ax += wsx[w]; ay += wsy[w]; }
    bsum[blockIdx.x].x = ax * (double)sc;
    bsum[blockIdx.x].y = ay * (double)sc;
  }
}

// Kernel 2: single-block fp64 exclusive scan of block sums (in place).
__global__ __launch_bounds__(B2) void wi_scan_blocks(DSum* bsum, int nblocks)
{
  const int t = threadIdx.x;
  const int per = (nblocks + B2 - 1) / B2;
  const int s = t * per;
  const int e = min(s + per, nblocks);
  double tx = 0.0, ty = 0.0;
  for (int i = s; i < e; ++i) { tx += bsum[i].x; ty += bsum[i].y; }
  __shared__ double lx[B2], ly[B2];
  lx[t] = tx; ly[t] = ty;
  __syncthreads();
  for (int off = 1; off < B2; off <<= 1) {
    double ax = lx[t], ay = ly[t];
    double bx = (t >= off) ? lx[t - off] : 0.0;
    double by = (t >= off) ? ly[t - off] : 0.0;
    __syncthreads();
    lx[t] = ax + bx; ly[t] = ay + by;
    __syncthreads();
  }
  double rx = (t > 0) ? lx[t - 1] : 0.0;
  double ry = (t > 0) ? ly[t - 1] : 0.0;
  for (int i = s; i < e; ++i) {
    double vx = bsum[i].x, vy = bsum[i].y;
    bsum[i].x = rx; bsum[i].y = ry;
    rx += vx; ry += vy;
  }
}

// Kernel 3: recompute uv, wave-shuffle scan, stage rows in LDS, emit with
// wave-contiguous NON-TEMPORAL stores (each instr = 1024 contiguous B/wave =
// full 128B lines -> safe to stream; avoids evicting U from L3).
__global__ __launch_bounds__(B3) void wi_emit(
    const float* __restrict__ U, const float* __restrict__ x0,
    const float* __restrict__ dtp, const DSum* __restrict__ boff,
    float* __restrict__ out, int N)
{
  __shared__ f32x4 stage[CH3];        // 2048 * 16 B = 32 KiB
  __shared__ float wsum_x[B3/64], wsum_y[B3/64];

  const int t = threadIdx.x;
  const int lane = t & 63, wid = t >> 6;
  const long base = (long)blockIdx.x * CH3 + (long)t * IT3;
  const float dt = *dtp;

  float vx[IT3], vy[IT3];
  const bool full = (base + IT3 <= (long)N);
  if (full) {
    const f32x4* p = (const f32x4*)(U + 2 * base);
    #pragma unroll
    for (int i = 0; i < IT3 / 2; ++i) {
      f32x4 a = p[i];
      vx[2*i]   = fast_tanh(a.x) * VMAX; vy[2*i]   = fast_tanh(a.y) * VMAX;
      vx[2*i+1] = fast_tanh(a.z) * VMAX; vy[2*i+1] = fast_tanh(a.w) * VMAX;
    }
  } else {
    for (int i = 0; i < IT3; ++i) {
      long idx = base + i;
      if (idx < N) { vx[i] = fast_tanh(U[2*idx]) * VMAX; vy[i] = fast_tanh(U[2*idx+1]) * VMAX; }
      else { vx[i] = 0.f; vy[i] = 0.f; }
    }
  }

  // thread-local inclusive prefix of uv*dt (fp32)
  float px[IT3], py[IT3];
  float sx = 0.f, sy = 0.f;
  #pragma unroll
  for (int i = 0; i < IT3; ++i) { sx += vx[i]*dt; px[i] = sx; sy += vy[i]*dt; py[i] = sy; }
  const float totx = sx, toty = sy;

  // wave-level inclusive scan of thread totals (fp32; tile sums small)
  #pragma unroll
  for (int o = 1; o < 64; o <<= 1) {
    float ux = __shfl_up(sx, o);
    float uy = __shfl_up(sy, o);
    if (lane >= o) { sx += ux; sy += uy; }
  }
  if (lane == 63) { wsum_x[wid] = sx; wsum_y[wid] = sy; }
  __syncthreads();
  float wbx = 0.f, wby = 0.f;
  #pragma unroll
  for (int w = 0; w < B3/64; ++w) {
    if (w < wid) { wbx += wsum_x[w]; wby += wsum_y[w]; }
  }
  const float exb = wbx + sx - totx;   // exclusive prefix within tile
  const float eyb = wby + sy - toty;

  const double ox = boff[blockIdx.x].x + (double)x0[0];
  const double oy = boff[blockIdx.x].y + (double)x0[1];

  // compute rows into LDS (XOR-swizzled so blocked writes + contiguous reads
  // both spread across bank groups)
  #pragma unroll
  for (int i = 0; i < IT3; ++i) {
    float posx = (float)(ox + (double)(exb + px[i]));
    float posy = (float)(oy + (double)(eyb + py[i]));
    float th = atan2f(vy[i], vx[i] + 1e-9f);
    float vv = fminf(sqrtf(vx[i]*vx[i] + vy[i]*vy[i] + 1e-12f), VMAX);
    f32x4 r; r.x = posx; r.y = posy; r.z = th; r.w = vv;
    const int k = t * IT3 + i;
    stage[k ^ ((k >> 3) & 7)] = r;
  }
  __syncthreads();

  // cooperative wave-contiguous non-temporal stores
  const long tile0 = (long)blockIdx.x * CH3;
  f32x4* o4 = (f32x4*)out;
  #pragma unroll
  for (int i = 0; i < IT3; ++i) {
    const int k = i * B3 + t;
    const long g = tile0 + k;
    if (g < (long)N) __builtin_nontemporal_store(stage[k ^ ((k >> 3) & 7)], o4 + 1 + g);
  }
  if (blockIdx.x == 0 && t == 0) {
    f32x4 r; r.x = x0[0]; r.y = x0[1]; r.z = x0[2]; r.w = x0[3];
    o4[0] = r;
  }
}

extern "C" void kernel_launch(void* const* d_in, const int* in_sizes, int n_in,
                              void* d_out, int out_size, void* d_ws, size_t ws_size,
                              hipStream_t stream) {
  const float* x0 = (const float*)d_in[0];
  const float* U  = (const float*)d_in[1];
  const float* dt = (const float*)d_in[2];
  float* out = (float*)d_out;
  const int N = in_sizes[1] / 2;
  const int nb1 = (N + CH1 - 1) / CH1;   // 8192
  const int nb3 = (N + CH3 - 1) / CH3;   // 8192 (CH1 == CH3)
  DSum* bsum = (DSum*)d_ws;              // nb1 * 16 B = 128 KiB

  wi_partial<<<nb1, B1, 0, stream>>>(U, dt, bsum, N);
  wi_scan_blocks<<<1, B2, 0, stream>>>(bsum, nb1);
  wi_emit<<<nb3, B3, 0, stream>>>(U, x0, dt, bsum, out, N);
}

// Round 7
// 108.539 us; speedup vs baseline: 21.0808x; 1.0076x over previous
//
#include <hip/hip_runtime.h>

#define B1 256
#define IT1 8                 // pairs per thread, kernel 1 (64B/lane)
#define CH1 (B1 * IT1)
#define B3 256
#define IT3 8                 // pairs per thread, kernel 3
#define CH3 (B3 * IT3)
#define B2 1024
#define VMAX 2.2f

typedef float f32x4 __attribute__((ext_vector_type(4)));

struct DSum { double x, y; };

__device__ __forceinline__ float fast_tanh(float x) {
  // tanh(x) = 1 - 2/(exp(2x)+1); exact at +/-inf, ~1e-6 abs error.
  float e = __expf(2.0f * x);
  return 1.0f - 2.0f / (e + 1.0f);
}

// atan2 via minimax atan poly on [0,1] + quadrant fixup. ~1e-4 rad abs error.
__device__ __forceinline__ float fast_atan2(float y, float x) {
  float ax = fabsf(x), ay = fabsf(y);
  float mn = fminf(ax, ay), mx = fmaxf(ax, ay);
  float a = mn / (mx + 1e-30f);
  float s = a * a;
  float r = ((-0.0464964749f * s + 0.15931422f) * s - 0.327622764f) * s * a + a;
  if (ay > ax) r = 1.57079637f - r;
  if (x < 0.0f) r = 3.14159274f - r;
  return copysignf(r, y);
}

// Kernel 1: per-block partial sums of tanh(U)*vmax*dt (fp32 in-block, fp64 out).
__global__ __launch_bounds__(B1) void wi_partial(
    const float* __restrict__ U, const float* __restrict__ dtp,
    DSum* __restrict__ bsum, int N)
{
  const int t = threadIdx.x;
  const int lane = t & 63, wid = t >> 6;
  const long base = (long)blockIdx.x * CH1 + (long)t * IT1;
  float sx = 0.f, sy = 0.f;
  if (base + IT1 <= (long)N) {
    const f32x4* p = (const f32x4*)(U + 2 * base);
    #pragma unroll
    for (int i = 0; i < IT1 / 2; ++i) {
      f32x4 a = p[i];
      sx += fast_tanh(a.x) + fast_tanh(a.z);
      sy += fast_tanh(a.y) + fast_tanh(a.w);
    }
  } else {
    for (int i = 0; i < IT1; ++i) {
      long idx = base + i;
      if (idx < N) { sx += fast_tanh(U[2*idx]); sy += fast_tanh(U[2*idx+1]); }
    }
  }
  // wave butterfly reduce (fp32)
  #pragma unroll
  for (int o = 1; o < 64; o <<= 1) { sx += __shfl_xor(sx, o); sy += __shfl_xor(sy, o); }
  __shared__ double wsx[B1/64], wsy[B1/64];
  if (lane == 0) { wsx[wid] = (double)sx; wsy[wid] = (double)sy; }
  __syncthreads();
  if (t == 0) {
    const float sc = VMAX * (*dtp);
    double ax = 0.0, ay = 0.0;
    #pragma unroll
    for (int w = 0; w < B1/64; ++w) { ax += wsx[w]; ay += wsy[w]; }
    bsum[blockIdx.x].x = ax * (double)sc;
    bsum[blockIdx.x].y = ay * (double)sc;
  }
}

// Kernel 2: single-block fp64 exclusive scan, wave-shuffle based (2 barriers).
__global__ __launch_bounds__(B2) void wi_scan_blocks(DSum* bsum, int nblocks)
{
  const int t = threadIdx.x;
  const int lane = t & 63, wid = t >> 6;   // 16 waves
  const int per = (nblocks + B2 - 1) / B2;
  const int s = t * per;
  const int e = min(s + per, nblocks);
  double tx = 0.0, ty = 0.0;
  for (int i = s; i < e; ++i) { tx += bsum[i].x; ty += bsum[i].y; }
  // wave-level inclusive shuffle scan of thread totals (fp64)
  double ix = tx, iy = ty;
  #pragma unroll
  for (int o = 1; o < 64; o <<= 1) {
    double ux = __shfl_up(ix, o);
    double uy = __shfl_up(iy, o);
    if (lane >= o) { ix += ux; iy += uy; }
  }
  __shared__ double wx[B2/64], wy[B2/64];
  if (lane == 63) { wx[wid] = ix; wy[wid] = iy; }
  __syncthreads();
  double wbx = 0.0, wby = 0.0;
  #pragma unroll
  for (int w = 0; w < B2/64; ++w) {
    if (w < wid) { wbx += wx[w]; wby += wy[w]; }
  }
  // exclusive prefix for this thread's first element
  double rx = wbx + ix - tx;
  double ry = wby + iy - ty;
  for (int i = s; i < e; ++i) {
    double vx = bsum[i].x, vy = bsum[i].y;
    bsum[i].x = rx; bsum[i].y = ry;
    rx += vx; ry += vy;
  }
}

// Kernel 3: recompute uv, wave-shuffle scan, stage rows in LDS, emit with
// wave-contiguous non-temporal stores (each instr = 1024 contiguous B/wave).
__global__ __launch_bounds__(B3) void wi_emit(
    const float* __restrict__ U, const float* __restrict__ x0,
    const float* __restrict__ dtp, const DSum* __restrict__ boff,
    float* __restrict__ out, int N)
{
  __shared__ f32x4 stage[CH3];        // 2048 * 16 B = 32 KiB
  __shared__ float wsum_x[B3/64], wsum_y[B3/64];

  const int t = threadIdx.x;
  const int lane = t & 63, wid = t >> 6;
  const long base = (long)blockIdx.x * CH3 + (long)t * IT3;
  const float dt = *dtp;

  float vx[IT3], vy[IT3];
  const bool full = (base + IT3 <= (long)N);
  if (full) {
    const f32x4* p = (const f32x4*)(U + 2 * base);
    #pragma unroll
    for (int i = 0; i < IT3 / 2; ++i) {
      f32x4 a = p[i];
      vx[2*i]   = fast_tanh(a.x) * VMAX; vy[2*i]   = fast_tanh(a.y) * VMAX;
      vx[2*i+1] = fast_tanh(a.z) * VMAX; vy[2*i+1] = fast_tanh(a.w) * VMAX;
    }
  } else {
    for (int i = 0; i < IT3; ++i) {
      long idx = base + i;
      if (idx < N) { vx[i] = fast_tanh(U[2*idx]) * VMAX; vy[i] = fast_tanh(U[2*idx+1]) * VMAX; }
      else { vx[i] = 0.f; vy[i] = 0.f; }
    }
  }

  // thread-local inclusive prefix of uv*dt (fp32)
  float px[IT3], py[IT3];
  float sx = 0.f, sy = 0.f;
  #pragma unroll
  for (int i = 0; i < IT3; ++i) { sx += vx[i]*dt; px[i] = sx; sy += vy[i]*dt; py[i] = sy; }
  const float totx = sx, toty = sy;

  // wave-level inclusive scan of thread totals (fp32)
  #pragma unroll
  for (int o = 1; o < 64; o <<= 1) {
    float ux = __shfl_up(sx, o);
    float uy = __shfl_up(sy, o);
    if (lane >= o) { sx += ux; sy += uy; }
  }
  if (lane == 63) { wsum_x[wid] = sx; wsum_y[wid] = sy; }
  __syncthreads();
  float wbx = 0.f, wby = 0.f;
  #pragma unroll
  for (int w = 0; w < B3/64; ++w) {
    if (w < wid) { wbx += wsum_x[w]; wby += wsum_y[w]; }
  }
  const float exb = wbx + sx - totx;   // exclusive prefix within tile
  const float eyb = wby + sy - toty;

  const double ox = boff[blockIdx.x].x + (double)x0[0];
  const double oy = boff[blockIdx.x].y + (double)x0[1];

  // compute rows into LDS (XOR-swizzled)
  #pragma unroll
  for (int i = 0; i < IT3; ++i) {
    float posx = (float)(ox + (double)(exb + px[i]));
    float posy = (float)(oy + (double)(eyb + py[i]));
    float th = fast_atan2(vy[i], vx[i] + 1e-9f);
    float vv = fminf(sqrtf(vx[i]*vx[i] + vy[i]*vy[i] + 1e-12f), VMAX);
    f32x4 r; r.x = posx; r.y = posy; r.z = th; r.w = vv;
    const int k = t * IT3 + i;
    stage[k ^ ((k >> 3) & 7)] = r;
  }
  __syncthreads();

  // cooperative wave-contiguous non-temporal stores
  const long tile0 = (long)blockIdx.x * CH3;
  f32x4* o4 = (f32x4*)out;
  #pragma unroll
  for (int i = 0; i < IT3; ++i) {
    const int k = i * B3 + t;
    const long g = tile0 + k;
    if (g < (long)N) __builtin_nontemporal_store(stage[k ^ ((k >> 3) & 7)], o4 + 1 + g);
  }
  if (blockIdx.x == 0 && t == 0) {
    f32x4 r; r.x = x0[0]; r.y = x0[1]; r.z = x0[2]; r.w = x0[3];
    o4[0] = r;
  }
}

extern "C" void kernel_launch(void* const* d_in, const int* in_sizes, int n_in,
                              void* d_out, int out_size, void* d_ws, size_t ws_size,
                              hipStream_t stream) {
  const float* x0 = (const float*)d_in[0];
  const float* U  = (const float*)d_in[1];
  const float* dt = (const float*)d_in[2];
  float* out = (float*)d_out;
  const int N = in_sizes[1] / 2;
  const int nb1 = (N + CH1 - 1) / CH1;   // 8192
  const int nb3 = (N + CH3 - 1) / CH3;   // 8192 (CH1 == CH3)
  DSum* bsum = (DSum*)d_ws;              // nb1 * 16 B = 128 KiB

  wi_partial<<<nb1, B1, 0, stream>>>(U, dt, bsum, N);
  wi_scan_blocks<<<1, B2, 0, stream>>>(bsum, nb1);
  wi_emit<<<nb3, B3, 0, stream>>>(U, x0, dt, bsum, out, N);
}